// Round 4
// baseline (583.900 us; speedup 1.0000x reference)
//
#include <hip/hip_runtime.h>
#include <hip/hip_bf16.h>
#include <stdint.h>

// ---------- helpers ----------
__device__ __forceinline__ uint16_t f2bf(float f) {
    union { float f; uint32_t u; } c; c.f = f;
    uint32_t u = c.u;
    return (uint16_t)((u + 0x7FFFu + ((u >> 16) & 1u)) >> 16);  // RNE
}
__device__ __forceinline__ uint32_t pack2(float a, float b) {
    return (uint32_t)f2bf(a) | ((uint32_t)f2bf(b) << 16);
}

typedef __bf16 bf16x8 __attribute__((ext_vector_type(8)));
typedef float  f32x16 __attribute__((ext_vector_type(16)));

#define GLOAD_LDS16(g, l) __builtin_amdgcn_global_load_lds( \
    (const __attribute__((address_space(1))) void*)(g),     \
    (__attribute__((address_space(3))) void*)(l), 16, 0, 0)

// ---------- Kernel 1: fused LayerNorm (blocks 0..M-1) + weight fp32->bf16 concat ----------
__global__ __launch_bounds__(256) void ln_wcvt(
    const float* __restrict__ x, const float* __restrict__ gw,
    const float* __restrict__ gb, uint16_t* __restrict__ y,
    const float* __restrict__ wq, const float* __restrict__ wk,
    const float* __restrict__ wv, uint16_t* __restrict__ wcat,
    int D, int M)
{
    const int t = threadIdx.x;
    if ((int)blockIdx.x < M) {
        // -------- LayerNorm: one block per row, D=2048 = 256 thr * 8 --------
        const size_t row = blockIdx.x;
        const float4* xr = (const float4*)(x + row * (size_t)D);
        float4 v0 = xr[2 * t], v1 = xr[2 * t + 1];

        float s  = v0.x + v0.y + v0.z + v0.w + v1.x + v1.y + v1.z + v1.w;
        float ss = v0.x * v0.x + v0.y * v0.y + v0.z * v0.z + v0.w * v0.w
                 + v1.x * v1.x + v1.y * v1.y + v1.z * v1.z + v1.w * v1.w;
#pragma unroll
        for (int off = 32; off > 0; off >>= 1) {
            s  += __shfl_down(s, off);
            ss += __shfl_down(ss, off);
        }
        __shared__ float red[10];
        const int wave = t >> 6, lane = t & 63;
        if (lane == 0) { red[wave] = s; red[4 + wave] = ss; }
        __syncthreads();
        if (t == 0) {
            float S  = red[0] + red[1] + red[2] + red[3];
            float SS = red[4] + red[5] + red[6] + red[7];
            float mu = S / (float)D;
            float var = SS / (float)D - mu * mu;
            red[8] = mu;
            red[9] = rsqrtf(var + 1e-5f);
        }
        __syncthreads();
        const float mu = red[8], rstd = red[9];

        const float4* wr = (const float4*)gw;
        const float4* br = (const float4*)gb;
        float4 w0 = wr[2 * t], w1 = wr[2 * t + 1];
        float4 b0 = br[2 * t], b1 = br[2 * t + 1];

        uint4 ov;
        ov.x = pack2((v0.x - mu) * rstd * w0.x + b0.x, (v0.y - mu) * rstd * w0.y + b0.y);
        ov.y = pack2((v0.z - mu) * rstd * w0.z + b0.z, (v0.w - mu) * rstd * w0.w + b0.w);
        ov.z = pack2((v1.x - mu) * rstd * w1.x + b1.x, (v1.y - mu) * rstd * w1.y + b1.y);
        ov.w = pack2((v1.z - mu) * rstd * w1.z + b1.z, (v1.w - mu) * rstd * w1.w + b1.w);
        ((uint4*)(y + row * (size_t)D))[t] = ov;
    } else {
        // -------- weight convert: [Wq;Wk;Wv] fp32 -> bf16 Wcat --------
        const size_t i = ((size_t)(blockIdx.x - M) * 256 + t) * 8;
        const size_t per = (size_t)D * D;            // elems per matrix (2^22)
        const int which = (int)(i / per);
        const float* src = (which == 0) ? wq : (which == 1) ? wk : wv;
        const size_t off = i - (size_t)which * per;
        float4 a = *(const float4*)(src + off);
        float4 b = *(const float4*)(src + off + 4);
        uint4 ov;
        ov.x = pack2(a.x, a.y);
        ov.y = pack2(a.z, a.w);
        ov.z = pack2(b.x, b.y);
        ov.w = pack2(b.z, b.w);
        *(uint4*)(wcat + i) = ov;
    }
}

// ---------- Kernel 2: C[M,N] = A[M,K] * Wcat[N,K]^T + bias, 32x32x16 bf16 MFMA ----------
// 128x128 block tile, BK=32, 4 waves (2x2 of 64x64), each wave 2x2 of 32x32 MFMA.
// global_load_lds width=16 staging (unpadded LDS, wave-uniform base + lane*16B).
__global__ __launch_bounds__(256) void qkv_gemm(
    const uint16_t* __restrict__ A, const uint16_t* __restrict__ W,
    const float* __restrict__ Bq, const float* __restrict__ Bk,
    const float* __restrict__ Bv,
    float* __restrict__ C, int M, int N, int K)
{
    __shared__ uint16_t As[128 * 32];
    __shared__ uint16_t Bs[128 * 32];

    const int t = threadIdx.x, wave = t >> 6, lane = t & 63;

    // swizzle: sweep M within groups of GROUPN col-blocks (L2/L3 locality)
    const int mbk = M >> 7;                  // 64
    const int GROUPN = 16;
    const int bpg = GROUPN * mbk;            // blocks per group
    const int g = blockIdx.x / bpg, r = blockIdx.x % bpg;
    const int nb = g * GROUPN + (r % GROUPN);
    const int mb = r / GROUPN;
    const int ncol0 = nb * 128;              // output col base = Wcat row base

    // staging: chunk = 16 rows x 32 cols = 512 elems = 64 lanes * 8 elems (16B)
    const int c0 = wave * 2, c1 = wave * 2 + 1;
    const int lrow = lane >> 2, lk = (lane & 3) * 8;
    const uint16_t* ga0 = A + (size_t)(mb * 128 + c0 * 16 + lrow) * K + lk;
    const uint16_t* ga1 = A + (size_t)(mb * 128 + c1 * 16 + lrow) * K + lk;
    const uint16_t* gb0 = W + (size_t)(ncol0 + c0 * 16 + lrow) * K + lk;
    const uint16_t* gb1 = W + (size_t)(ncol0 + c1 * 16 + lrow) * K + lk;
    uint16_t* la0 = &As[c0 * 512];
    uint16_t* la1 = &As[c1 * 512];
    uint16_t* lb0 = &Bs[c0 * 512];
    uint16_t* lb1 = &Bs[c1 * 512];

    f32x16 acc[2][2] = {};

    const int wm = (wave >> 1) * 64, wn = (wave & 1) * 64;
    // 32x32x16 A/B operand layout: m(n) = lane&31, k = (lane>>5)*8 + j
    const int fm = lane & 31, fk = (lane >> 5) * 8;

    for (int kt = 0; kt < K; kt += 32) {
        GLOAD_LDS16(ga0, la0);
        GLOAD_LDS16(ga1, la1);
        GLOAD_LDS16(gb0, lb0);
        GLOAD_LDS16(gb1, lb1);
        ga0 += 32; ga1 += 32; gb0 += 32; gb1 += 32;
        __syncthreads();   // drains vmcnt -> LDS tiles valid

#pragma unroll
        for (int kk = 0; kk < 2; ++kk) {
            bf16x8 a0 = *(const bf16x8*)&As[(wm      + fm) * 32 + kk * 16 + fk];
            bf16x8 a1 = *(const bf16x8*)&As[(wm + 32 + fm) * 32 + kk * 16 + fk];
            bf16x8 b0 = *(const bf16x8*)&Bs[(wn      + fm) * 32 + kk * 16 + fk];
            bf16x8 b1 = *(const bf16x8*)&Bs[(wn + 32 + fm) * 32 + kk * 16 + fk];
            acc[0][0] = __builtin_amdgcn_mfma_f32_32x32x16_bf16(a0, b0, acc[0][0], 0, 0, 0);
            acc[0][1] = __builtin_amdgcn_mfma_f32_32x32x16_bf16(a0, b1, acc[0][1], 0, 0, 0);
            acc[1][0] = __builtin_amdgcn_mfma_f32_32x32x16_bf16(a1, b0, acc[1][0], 0, 0, 0);
            acc[1][1] = __builtin_amdgcn_mfma_f32_32x32x16_bf16(a1, b1, acc[1][1], 0, 0, 0);
        }
        __syncthreads();   // protect LDS before next staging
    }

    // epilogue: 32x32 C/D layout col = lane&31, row = (reg&3) + 8*(reg>>2) + 4*(lane>>5)
    const int rq = 4 * (lane >> 5);
#pragma unroll
    for (int ni = 0; ni < 2; ++ni) {
        const int colg = ncol0 + wn + ni * 32 + fm;     // global col in [0, N)
        const int which = (colg >= 2 * K) ? 2 : (colg >= K ? 1 : 0);
        const float* bp = (which == 0) ? Bq : (which == 1) ? Bk : Bv;
        const float bj = bp[colg - which * K];
#pragma unroll
        for (int mi = 0; mi < 2; ++mi) {
            const int rbase = mb * 128 + wm + mi * 32 + rq;
#pragma unroll
            for (int reg = 0; reg < 16; ++reg) {
                const int row = rbase + (reg & 3) + 8 * (reg >> 2);
                C[(size_t)row * N + colg] = acc[mi][ni][reg] + bj;
            }
        }
    }
}

extern "C" void kernel_launch(void* const* d_in, const int* in_sizes, int n_in,
                              void* d_out, int out_size, void* d_ws, size_t ws_size,
                              hipStream_t stream) {
    const float* x  = (const float*)d_in[0];
    const float* nw = (const float*)d_in[1];
    const float* nb = (const float*)d_in[2];
    const float* wq = (const float*)d_in[3];
    const float* bq = (const float*)d_in[4];
    const float* wk = (const float*)d_in[5];
    const float* bk = (const float*)d_in[6];
    const float* wv = (const float*)d_in[7];
    const float* bv = (const float*)d_in[8];

    const int D = in_sizes[1];        // 2048
    const int M = in_sizes[0] / D;    // 8192 (B*S)
    const int N = 3 * D;              // 6144

    // ws layout: [normed bf16: M*D] [Wcat bf16: N*D]  (32 MB + 24 MB)
    uint16_t* normed = (uint16_t*)d_ws;
    uint16_t* wcat   = normed + (size_t)M * D;

    const int wcvt_blocks = (int)(((size_t)N * D) / (256 * 8));   // 6144
    ln_wcvt<<<M + wcvt_blocks, 256, 0, stream>>>(x, nw, nb, normed,
                                                 wq, wk, wv, wcat, D, M);
    const int nblocks = (M / 128) * (N / 128);                    // 3072
    qkv_gemm<<<nblocks, 256, 0, stream>>>(normed, wcat, bq, bk, bv,
                                          (float*)d_out, M, N, D);
}